// Round 8
// baseline (478.507 us; speedup 1.0000x reference)
//
#include <hip/hip_runtime.h>
#include <hip/hip_bf16.h>
#include <stdint.h>

typedef unsigned short u16;
typedef unsigned int u32;

// ---- problem constants ----
#define HEADS  8
#define DH     32
#define BLK    8
#define HALO   3
#define WINSZ  14
#define QKSCALE 0.17677669529663689f   // 32^-0.5
#define LOG2E   1.4426950408889634f
#define QS2     (QKSCALE * LOG2E)      // scores in log2 domain

// ---- workspace layout (bytes) ----
#define WS_XT   ((size_t)0)                    // xt bf16 [B*16384][256]: 33,554,432
#define WS_WB   ((size_t)33554432)             // w bf16 [768][256] (q,k,v): 393,216
#define WS_FCWB (WS_WB + 393216)               // fc_w bf16 [256][256]: 131,072
#define WS_FCB  (WS_FCWB + 131072)             // fc_b fp32: 1,024
#define WS_RH   (WS_FCB + 1024)                // rel_h fp32: 3,456
#define WS_RW   (WS_RH + 3456)                 // rel_w fp32: 3,456
#define WS_FLAG (WS_RW + 3456)                 // int flag
#define WS_Q    ((size_t)34611200)             // q bf16 [65536][256]: 33,554,432
#define WS_KV   (WS_Q + 33554432)              // kv bf16 [65536][512]: 67,108,864
#define WS_CTX  (WS_KV + 67108864)             // ctx bf16 [B*256 blk][64][256]: 33,554,432

typedef float f32x4 __attribute__((ext_vector_type(4)));
typedef short s16x8 __attribute__((ext_vector_type(8)));
typedef short s16x4 __attribute__((ext_vector_type(4)));

__device__ __forceinline__ float bflo(u32 u){ return __uint_as_float(u << 16); }
__device__ __forceinline__ float bfhi(u32 u){ return __uint_as_float(u & 0xffff0000u); }
__device__ __forceinline__ float bf2f(u16 h){ return __uint_as_float(((u32)h) << 16); }
__device__ __forceinline__ u16 f2bf(float f){
    u32 u = __float_as_uint(f);
    u32 r = (u + 0x7fffu + ((u >> 16) & 1u)) >> 16;   // RNE
    return (u16)r;
}

// NOTE: __has_builtin guards on amdgcn builtins must live inside
// __HIP_DEVICE_COMPILE__ — host pass picks the wrong branch otherwise (R3).
#if defined(__HIP_DEVICE_COMPILE__)
__device__ __forceinline__ f32x4 mfma16(s16x4 a, s16x4 b, f32x4 c){
    return __builtin_amdgcn_mfma_f32_16x16x16bf16_1k(a, b, c, 0, 0, 0);
}
#else
__device__ __forceinline__ f32x4 mfma16(s16x4 a, s16x4 b, f32x4 c){ return c; }
#endif

#if defined(__HIP_DEVICE_COMPILE__) && __has_builtin(__builtin_amdgcn_exp2f)
__device__ __forceinline__ float exp2fast(float x){ return __builtin_amdgcn_exp2f(x); }
#else
__device__ __forceinline__ float exp2fast(float x){ return exp2f(x); }
#endif

// ---------------- dtype detector ----------------
__global__ void k_detect(const u16* __restrict__ x, int* __restrict__ flag){
    int t = threadIdx.x;
    int wild = 0;
    for (int i = t; i < 1024; i += 64){
        u16 u = x[2*i];
        int ef = (u >> 7) & 0xff;
        if (ef >= 0x90) wild = 1;
    }
    int any = __any(wild);
    if (t == 0) *flag = any ? 1 : 0;
}

// ---------------- canonicalize + transpose x -> xt[pix][c] bf16 ----------------
// tile: 64 c x 64 pix per block via LDS
__global__ __launch_bounds__(256)
void k_canon_xt(const void* __restrict__ src, u16* __restrict__ dst,
                const int* __restrict__ flag){
    __shared__ u32 xsu[64][33];
    const int tile = blockIdx.x;                 // [b(4)][ct(4)][pt(256)]
    const int pt = tile & 255, ct = (tile >> 8) & 3, b = tile >> 10;
    const int pix0 = pt * 64, c0 = ct * 64;
    const int t = threadIdx.x;
    const int isf = *flag;
    if (isf){
        const float* s = (const float*)src;
        #pragma unroll
        for (int rep = 0; rep < 8; ++rep){
            int f = rep * 256 + t;
            int c = f >> 5, pu = f & 31;
            const float2 v = *(const float2*)(s + ((size_t)b*256 + c0 + c)*16384 + pix0 + pu*2);
            xsu[c][pu] = (u32)f2bf(v.x) | ((u32)f2bf(v.y) << 16);
        }
    } else {
        const u32* s = (const u32*)src;
        #pragma unroll
        for (int rep = 0; rep < 8; ++rep){
            int f = rep * 256 + t;
            int c = f >> 5, pu = f & 31;
            xsu[c][pu] = s[(((size_t)b*256 + c0 + c)*16384 + pix0)/2 + pu];
        }
    }
    __syncthreads();
    #pragma unroll
    for (int rep = 0; rep < 2; ++rep){
        int f = rep * 256 + t;                   // 512 = 64 pix x 8 c-groups
        int pix = f >> 3, cu8 = f & 7;
        u32 pk[4];
        #pragma unroll
        for (int d = 0; d < 4; ++d){
            u32 a = xsu[cu8*8 + 2*d][pix >> 1];
            u32 bb = xsu[cu8*8 + 2*d + 1][pix >> 1];
            u16 ha = (pix & 1) ? (u16)(a >> 16) : (u16)(a & 0xffffu);
            u16 hb = (pix & 1) ? (u16)(bb >> 16) : (u16)(bb & 0xffffu);
            pk[d] = (u32)ha | ((u32)hb << 16);
        }
        *(uint4*)(dst + ((size_t)b*16384 + pix0 + pix)*256 + c0 + cu8*8) = *(uint4*)pk;
    }
}

// ---------------- canonicalize weights -> bf16 [o][c] ----------------
__global__ void k_canon_w(const void* __restrict__ wq, const void* __restrict__ wkv,
                          const void* __restrict__ fcw, u16* __restrict__ wb,
                          u16* __restrict__ fcwb, const int* __restrict__ flag){
    const int isf = *flag;
    int i = blockIdx.x * 256 + threadIdx.x;      // 262144 total
    if (i < 196608){
        int o = i >> 8, c = i & 255;
        const void* src = (o < 256) ? wq : wkv;
        int oo = (o < 256) ? o : o - 256;
        float v = isf ? ((const float*)src)[oo*256 + c] : bf2f(((const u16*)src)[oo*256 + c]);
        wb[i] = f2bf(v);
    } else {
        int j = i - 196608;
        float v = isf ? ((const float*)fcw)[j] : bf2f(((const u16*)fcw)[j]);
        fcwb[j] = f2bf(v);
    }
}

// ---------------- canonicalize small tensors -> fp32 ----------------
__global__ void k_canon_f(const void* __restrict__ src, float* __restrict__ dst, int n,
                          const int* __restrict__ flag){
    const int isf = *flag;
    int i = blockIdx.x * 256 + threadIdx.x;
    if (i < n){
        dst[i] = isf ? ((const float*)src)[i] : bf2f(((const u16*)src)[i]);
    }
}

// ---------------- MFMA QKV projection (R12: 16 pix/wave) ----------------
// R11 post-mortem: ot-split quadrupled HBM traffic (partial-line writebacks
// + L3-missed xt re-reads) — reverted. Occupancy raised instead by halving
// pixels/wave 32->16 (1 B-frag n-tile): 4096 waves, grid 1024 = 4 blocks/CU
// = 16 waves/CU, traffic IDENTICAL to R10 (each pixel owned by one wave).
__global__ __launch_bounds__(256)
void k_proj(const u16* __restrict__ xt, const u16* __restrict__ wb,
            u16* __restrict__ qo, u16* __restrict__ kvo){
    const int t = threadIdx.x;
    const int wave = t >> 6, lane = t & 63;
    const int quad = lane >> 4, l15 = lane & 15;
    const int p0 = blockIdx.x * 64 + wave * 16;

    s16x8 bf[8];
    {
        const u16* row = xt + (size_t)(p0 + l15) * 256 + quad * 8;
        #pragma unroll
        for (int kc = 0; kc < 8; ++kc)
            bf[kc] = *(const s16x8*)(row + kc * 32);
    }

    for (int ot = 0; ot < 48; ++ot){
        const u16* arow = wb + (size_t)(ot*16 + l15) * 256 + quad * 8;
        s16x8 af[8];
        #pragma unroll
        for (int kc = 0; kc < 8; ++kc)
            af[kc] = *(const s16x8*)(arow + kc * 32);
        f32x4 acc = {0.f,0.f,0.f,0.f};
        #pragma unroll
        for (int kc = 0; kc < 8; ++kc)
            acc = __builtin_amdgcn_mfma_f32_16x16x32_bf16(af[kc], bf[kc], acc, 0,0,0);
        const int o = ot*16 + quad*4;
        const size_t pix = p0 + l15;
        uint2 st;
        st.x = (u32)f2bf(acc[0]) | ((u32)f2bf(acc[1]) << 16);
        st.y = (u32)f2bf(acc[2]) | ((u32)f2bf(acc[3]) << 16);
        if (ot < 16) *(uint2*)(qo  + pix*256 + o)        = st;
        else         *(uint2*)(kvo + pix*512 + (o - 256)) = st;
    }
}

// ---------------- MFMA halo attention (unchanged from R10) ----------------
__global__ __launch_bounds__(512)
void k_attn(const u16* __restrict__ qc, const u16* __restrict__ kvc,
            const float* __restrict__ rh, const float* __restrict__ rw,
            u16* __restrict__ ctx){
    __shared__ __align__(16) u16 kvb[2][15][520];
    __shared__ u16 bht[8][21][64];
    const int t = threadIdx.x;
    const int head = t >> 6, lane = t & 63;
    const int quad = lane >> 4, l15 = lane & 15;
    const int blk = blockIdx.x, b = blockIdx.y;
    const int r0 = (blk >> 4) * 8, c0 = (blk & 15) * 8;

    s16x8 qf[4];
    #pragma unroll
    for (int nt = 0; nt < 4; ++nt){
        int q = nt*16 + l15;
        size_t pix = (size_t)b*16384 + (size_t)(r0 + (q>>3))*128 + (c0 + (q&7));
        qf[nt] = *(const s16x8*)(qc + pix*256 + head*32 + quad*8);
    }

    const int j0 = t >> 6;
    const int ch0 = (t & 63) * 8;

    {   // pre-stage tile 0
        int hh = r0 - 3;
        bool vh = (hh >= 0 && hh < 128);
        int ww0 = c0 - 3 + j0, ww1 = ww0 + 8;
        uint4 v0 = make_uint4(0,0,0,0), v1 = make_uint4(0,0,0,0);
        if (vh && ww0 >= 0 && ww0 < 128)
            v0 = *(const uint4*)(kvc + ((size_t)b*16384 + (size_t)hh*128 + ww0)*512 + ch0);
        if (vh && (j0+8) < 14 && ww1 >= 0 && ww1 < 128)
            v1 = *(const uint4*)(kvc + ((size_t)b*16384 + (size_t)hh*128 + ww1)*512 + ch0);
        *(uint4*)&kvb[0][j0][ch0] = v0;
        if (j0 + 8 < 15) *(uint4*)&kvb[0][j0+8][ch0] = v1;   // rows 8..14; row14 <- zeros
    }

    float bwreg[4][4];
    {
        f32x4 d[2][4];
        #pragma unroll
        for (int mt = 0; mt < 2; ++mt){
            int u = mt*16 + l15;
            s16x8 af;
            #pragma unroll
            for (int i2 = 0; i2 < 8; ++i2) af[i2] = 0;
            if (u <= 26){
                float4 a0 = *(const float4*)(rw + u*32 + quad*8);
                float4 a1 = *(const float4*)(rw + u*32 + quad*8 + 4);
                af[0]=(short)f2bf(a0.x); af[1]=(short)f2bf(a0.y);
                af[2]=(short)f2bf(a0.z); af[3]=(short)f2bf(a0.w);
                af[4]=(short)f2bf(a1.x); af[5]=(short)f2bf(a1.y);
                af[6]=(short)f2bf(a1.z); af[7]=(short)f2bf(a1.w);
            }
            #pragma unroll
            for (int nt = 0; nt < 4; ++nt){
                f32x4 z = {0.f,0.f,0.f,0.f};
                d[mt][nt] = __builtin_amdgcn_mfma_f32_16x16x32_bf16(af, qf[nt], z, 0,0,0);
            }
        }
        #pragma unroll
        for (int mt = 0; mt < 2; ++mt)
            #pragma unroll
            for (int nt = 0; nt < 4; ++nt)
                #pragma unroll
                for (int r = 0; r < 4; ++r){
                    int u = mt*16 + quad*4 + r;
                    if (u >= 6 && u <= 26)
                        bht[head][u-6][nt*16 + l15] = f2bf(d[mt][nt][r] * LOG2E);
                }
        __syncthreads();
        #pragma unroll
        for (int nt = 0; nt < 4; ++nt){
            int q = nt*16 + l15, qy = l15 & 7;
            #pragma unroll
            for (int r = 0; r < 4; ++r){
                int j = quad*4 + r;
                bwreg[nt][r] = (j < 14) ? bf2f(bht[head][j + 7 - qy][q]) : -1e30f;
            }
        }
        __syncthreads();
        #pragma unroll
        for (int mt = 0; mt < 2; ++mt){
            int u = mt*16 + l15;
            s16x8 af;
            #pragma unroll
            for (int i2 = 0; i2 < 8; ++i2) af[i2] = 0;
            if (u <= 26){
                float4 a0 = *(const float4*)(rh + u*32 + quad*8);
                float4 a1 = *(const float4*)(rh + u*32 + quad*8 + 4);
                af[0]=(short)f2bf(a0.x); af[1]=(short)f2bf(a0.y);
                af[2]=(short)f2bf(a0.z); af[3]=(short)f2bf(a0.w);
                af[4]=(short)f2bf(a1.x); af[5]=(short)f2bf(a1.y);
                af[6]=(short)f2bf(a1.z); af[7]=(short)f2bf(a1.w);
            }
            #pragma unroll
            for (int nt = 0; nt < 4; ++nt){
                f32x4 z = {0.f,0.f,0.f,0.f};
                d[mt][nt] = __builtin_amdgcn_mfma_f32_16x16x32_bf16(af, qf[nt], z, 0,0,0);
            }
        }
        #pragma unroll
        for (int mt = 0; mt < 2; ++mt)
            #pragma unroll
            for (int nt = 0; nt < 4; ++nt)
                #pragma unroll
                for (int r = 0; r < 4; ++r){
                    int u = mt*16 + quad*4 + r;
                    if (u >= 6 && u <= 26)
                        bht[head][u-6][nt*16 + l15] = f2bf(d[mt][nt][r] * LOG2E);
                }
    }

    const int krow = (l15 < 15) ? l15 : 14;   // clamped K row (row14 == zeros)

    float m_[4] = {-1e30f,-1e30f,-1e30f,-1e30f};
    float l_[4] = {0.f,0.f,0.f,0.f};
    f32x4 O[2][4];
    #pragma unroll
    for (int mt = 0; mt < 2; ++mt)
        #pragma unroll
        for (int nt = 0; nt < 4; ++nt){ f32x4 z = {0.f,0.f,0.f,0.f}; O[mt][nt] = z; }

    #pragma unroll 2
    for (int tile = 0; tile < 14; ++tile){
        uint4 p0 = make_uint4(0,0,0,0), p1 = make_uint4(0,0,0,0);
        if (tile < 13){
            int hh = r0 - 3 + tile + 1;
            bool vh = (hh >= 0 && hh < 128);
            int ww0 = c0 - 3 + j0, ww1 = ww0 + 8;
            if (vh && ww0 >= 0 && ww0 < 128)
                p0 = *(const uint4*)(kvc + ((size_t)b*16384 + (size_t)hh*128 + ww0)*512 + ch0);
            if (vh && (j0+8) < 14 && ww1 >= 0 && ww1 < 128)
                p1 = *(const uint4*)(kvc + ((size_t)b*16384 + (size_t)hh*128 + ww1)*512 + ch0);
        }
        __syncthreads();
        const u16* kb = &kvb[tile & 1][0][0];

        s16x8 ak = *(const s16x8*)(kb + krow*520 + head*32 + quad*8);
        f32x4 sc[4];
        #pragma unroll
        for (int nt = 0; nt < 4; ++nt){
            f32x4 z = {0.f,0.f,0.f,0.f};
            sc[nt] = __builtin_amdgcn_mfma_f32_16x16x32_bf16(ak, qf[nt], z, 0,0,0);
        }
        s16x4 av[2];
        #pragma unroll
        for (int mt = 0; mt < 2; ++mt)
            #pragma unroll
            for (int i = 0; i < 4; ++i){
                int vr = quad*4 + i; vr = (vr < 15) ? vr : 14;   // row14 == zeros
                av[mt][i] = (short)kb[vr*520 + 256 + head*32 + mt*16 + l15];
            }

        #pragma unroll
        for (int nt = 0; nt < 4; ++nt){
            int q = nt*16 + l15;
            int qx = q >> 3;
            float bh = bf2f(bht[head][tile + 7 - qx][q]);
            float s0 = fmaf(sc[nt][0], QS2, bwreg[nt][0] + bh);
            float s1 = fmaf(sc[nt][1], QS2, bwreg[nt][1] + bh);
            float s2 = fmaf(sc[nt][2], QS2, bwreg[nt][2] + bh);
            float s3 = fmaf(sc[nt][3], QS2, bwreg[nt][3] + bh);
            float mx = fmaxf(fmaxf(s0, s1), fmaxf(s2, s3));
            mx = fmaxf(mx, __shfl_xor(mx, 16));
            mx = fmaxf(mx, __shfl_xor(mx, 32));
            float mn = fmaxf(m_[nt], mx);
            float al = exp2fast(m_[nt] - mn);
            m_[nt] = mn;
            float e0 = exp2fast(s0 - mn), e1 = exp2fast(s1 - mn);
            float e2 = exp2fast(s2 - mn), e3 = exp2fast(s3 - mn);
            l_[nt] = l_[nt] * al + ((e0 + e1) + (e2 + e3));   // per-lane partial
            s16x4 pp;
            pp[0] = (short)f2bf(e0); pp[1] = (short)f2bf(e1);
            pp[2] = (short)f2bf(e2); pp[3] = (short)f2bf(e3);
            #pragma unroll
            for (int mt = 0; mt < 2; ++mt){
                f32x4 o = O[mt][nt];
                o[0] *= al; o[1] *= al; o[2] *= al; o[3] *= al;
                O[mt][nt] = mfma16(av[mt], pp, o);
            }
        }
        if (tile < 13){
            int nb = (tile + 1) & 1;
            *(uint4*)&kvb[nb][j0][ch0] = p0;
            if (j0 + 8 < 15) *(uint4*)&kvb[nb][j0+8][ch0] = p1;   // row14 <- zeros
        }
    }

    #pragma unroll
    for (int nt = 0; nt < 4; ++nt){
        float l = l_[nt];
        l += __shfl_xor(l, 16);
        l += __shfl_xor(l, 32);
        float inv = 1.f / l;
        int q = nt*16 + l15;
        size_t base = (((size_t)(b*256 + blk))*64 + q)*256 + head*32 + quad*4;
        #pragma unroll
        for (int mt = 0; mt < 2; ++mt){
            f32x4 o = O[mt][nt];
            u32 w0 = (u32)f2bf(o[0]*inv) | ((u32)f2bf(o[1]*inv) << 16);
            u32 w1 = (u32)f2bf(o[2]*inv) | ((u32)f2bf(o[3]*inv) << 16);
            uint2 st; st.x = w0; st.y = w1;
            *(uint2*)(ctx + base + mt*16) = st;
        }
    }
}

// ---------------- MFMA output projection + bias (R12: 16 pix/wave) ----------------
// Same occupancy fix as k_proj: 1 m-tile per wave, grid 1024, full ot loop
// (no ot split — R11's traffic lesson), traffic identical to R10.
__global__ __launch_bounds__(256)
void k_out(const u16* __restrict__ ctx, const u16* __restrict__ fcwb,
           const float* __restrict__ fcb, void* __restrict__ outp,
           const int* __restrict__ flag){
    const int t = threadIdx.x;
    const int wave = t >> 6, lane = t & 63;
    const int quad = lane >> 4, l15 = lane & 15;
    const int p0 = blockIdx.x * 64 + wave * 16;
    const int b = p0 >> 14;
    const int h = (p0 >> 7) & 127, w0 = p0 & 127;
    const int isf32 = *flag;

    s16x8 af[8];
    {
        int w = w0 + l15;
        int blkid = (h >> 3) * 16 + (w >> 3);
        int qi = (h & 7) * 8 + (w & 7);
        const u16* row = ctx + ((size_t)(b*256 + blkid)*64 + qi) * 256 + quad * 8;
        #pragma unroll
        for (int kc = 0; kc < 8; ++kc)
            af[kc] = *(const s16x8*)(row + kc * 32);
    }

    for (int ot = 0; ot < 16; ++ot){
        const u16* brow = fcwb + (size_t)(ot*16 + l15) * 256 + quad * 8;
        s16x8 bfr[8];
        #pragma unroll
        for (int kc = 0; kc < 8; ++kc)
            bfr[kc] = *(const s16x8*)(brow + kc * 32);
        f32x4 acc = {0.f,0.f,0.f,0.f};
        #pragma unroll
        for (int kc = 0; kc < 8; ++kc)
            acc = __builtin_amdgcn_mfma_f32_16x16x32_bf16(af[kc], bfr[kc], acc, 0,0,0);
        const float bias = fcb[ot*16 + l15];
        const int wv = w0 + quad*4;
        const size_t obase = (size_t)b*4194304 + (size_t)(ot*16 + l15)*16384
                           + (size_t)h*128 + wv;
        if (isf32){
            float4 v;
            v.x = acc[0] + bias; v.y = acc[1] + bias;
            v.z = acc[2] + bias; v.w = acc[3] + bias;
            *(float4*)((float*)outp + obase) = v;
        } else {
            uint2 v;
            v.x = (u32)f2bf(acc[0] + bias) | ((u32)f2bf(acc[1] + bias) << 16);
            v.y = (u32)f2bf(acc[2] + bias) | ((u32)f2bf(acc[3] + bias) << 16);
            *(uint2*)((u16*)outp + obase) = v;
        }
    }
}

extern "C" void kernel_launch(void* const* d_in, const int* in_sizes, int n_in,
                              void* d_out, int out_size, void* d_ws, size_t ws_size,
                              hipStream_t stream){
    const void* x    = d_in[0];
    const void* wq   = d_in[1];
    const void* wkv  = d_in[2];
    const void* fcw  = d_in[3];
    const void* fcb  = d_in[4];
    const void* relh = d_in[5];
    const void* relw = d_in[6];

    char* ws = (char*)d_ws;
    u16*   xt   = (u16*)(ws + WS_XT);
    u16*   wb   = (u16*)(ws + WS_WB);
    u16*   fcwb = (u16*)(ws + WS_FCWB);
    float* fcbf = (float*)(ws + WS_FCB);
    float* rhf  = (float*)(ws + WS_RH);
    float* rwf  = (float*)(ws + WS_RW);
    int*   flag = (int*)(ws + WS_FLAG);
    u16*   qb   = (u16*)(ws + WS_Q);
    u16*   kvb  = (u16*)(ws + WS_KV);
    u16*   ctxb = (u16*)(ws + WS_CTX);

    k_detect<<<1, 64, 0, stream>>>((const u16*)x, flag);
    k_canon_xt<<<4096, 256, 0, stream>>>(x, xt, flag);
    k_canon_w<<<1024, 256, 0, stream>>>(wq, wkv, fcw, wb, fcwb, flag);
    k_canon_f<<<1, 256, 0, stream>>>(fcb,  fcbf, 256, flag);
    k_canon_f<<<4, 256, 0, stream>>>(relh, rhf,  864, flag);
    k_canon_f<<<4, 256, 0, stream>>>(relw, rwf,  864, flag);

    k_proj<<<1024, 256, 0, stream>>>(xt, wb, qb, kvb);
    dim3 ga(256, 4);
    k_attn<<<ga, 512, 0, stream>>>(qb, kvb, rhf, rwf, ctxb);
    k_out<<<1024, 256, 0, stream>>>(ctxb, fcwb, fcbf, d_out, flag);
}

// Round 9
// 300.747 us; speedup vs baseline: 1.5911x; 1.5911x over previous
//
#include <hip/hip_runtime.h>
#include <hip/hip_bf16.h>
#include <stdint.h>

typedef unsigned short u16;
typedef unsigned int u32;

// ---- problem constants ----
#define HEADS  8
#define DH     32
#define BLK    8
#define HALO   3
#define WINSZ  14
#define QKSCALE 0.17677669529663689f   // 32^-0.5
#define LOG2E   1.4426950408889634f
#define QS2     (QKSCALE * LOG2E)      // scores in log2 domain

// ---- workspace layout (bytes) ----
#define WS_XT   ((size_t)0)                    // xt bf16 [B*16384][256]: 33,554,432
#define WS_WB   ((size_t)33554432)             // w bf16 [768][256] (q,k,v): 393,216
#define WS_FCWB (WS_WB + 393216)               // fc_w bf16 [256][256]: 131,072
#define WS_FCB  (WS_FCWB + 131072)             // fc_b fp32: 1,024
#define WS_RH   (WS_FCB + 1024)                // rel_h fp32: 3,456
#define WS_RW   (WS_RH + 3456)                 // rel_w fp32: 3,456
#define WS_FLAG (WS_RW + 3456)                 // int flag
#define WS_Q    ((size_t)34611200)             // q bf16 [65536][256]: 33,554,432
#define WS_KV   (WS_Q + 33554432)              // kv bf16 [65536][512]: 67,108,864
#define WS_CTX  (WS_KV + 67108864)             // ctx bf16 [B*256 blk][64][256]: 33,554,432

typedef float f32x4 __attribute__((ext_vector_type(4)));
typedef short s16x8 __attribute__((ext_vector_type(8)));
typedef short s16x4 __attribute__((ext_vector_type(4)));

__device__ __forceinline__ float bflo(u32 u){ return __uint_as_float(u << 16); }
__device__ __forceinline__ float bfhi(u32 u){ return __uint_as_float(u & 0xffff0000u); }
__device__ __forceinline__ float bf2f(u16 h){ return __uint_as_float(((u32)h) << 16); }
__device__ __forceinline__ u16 f2bf(float f){
    u32 u = __float_as_uint(f);
    u32 r = (u + 0x7fffu + ((u >> 16) & 1u)) >> 16;   // RNE
    return (u16)r;
}

// NOTE: __has_builtin guards on amdgcn builtins must live inside
// __HIP_DEVICE_COMPILE__ — host pass picks the wrong branch otherwise (R3).
#if defined(__HIP_DEVICE_COMPILE__)
__device__ __forceinline__ f32x4 mfma16(s16x4 a, s16x4 b, f32x4 c){
    return __builtin_amdgcn_mfma_f32_16x16x16bf16_1k(a, b, c, 0, 0, 0);
}
#else
__device__ __forceinline__ f32x4 mfma16(s16x4 a, s16x4 b, f32x4 c){ return c; }
#endif

#if defined(__HIP_DEVICE_COMPILE__) && __has_builtin(__builtin_amdgcn_exp2f)
__device__ __forceinline__ float exp2fast(float x){ return __builtin_amdgcn_exp2f(x); }
#else
__device__ __forceinline__ float exp2fast(float x){ return exp2f(x); }
#endif

// ---------------- dtype detector ----------------
__global__ void k_detect(const u16* __restrict__ x, int* __restrict__ flag){
    int t = threadIdx.x;
    int wild = 0;
    for (int i = t; i < 1024; i += 64){
        u16 u = x[2*i];
        int ef = (u >> 7) & 0xff;
        if (ef >= 0x90) wild = 1;
    }
    int any = __any(wild);
    if (t == 0) *flag = any ? 1 : 0;
}

// ---------------- canonicalize + transpose x -> xt[pix][c] bf16 ----------------
// tile: 64 c x 64 pix per block via LDS
__global__ __launch_bounds__(256)
void k_canon_xt(const void* __restrict__ src, u16* __restrict__ dst,
                const int* __restrict__ flag){
    __shared__ u32 xsu[64][33];
    const int tile = blockIdx.x;                 // [b(4)][ct(4)][pt(256)]
    const int pt = tile & 255, ct = (tile >> 8) & 3, b = tile >> 10;
    const int pix0 = pt * 64, c0 = ct * 64;
    const int t = threadIdx.x;
    const int isf = *flag;
    if (isf){
        const float* s = (const float*)src;
        #pragma unroll
        for (int rep = 0; rep < 8; ++rep){
            int f = rep * 256 + t;
            int c = f >> 5, pu = f & 31;
            const float2 v = *(const float2*)(s + ((size_t)b*256 + c0 + c)*16384 + pix0 + pu*2);
            xsu[c][pu] = (u32)f2bf(v.x) | ((u32)f2bf(v.y) << 16);
        }
    } else {
        const u32* s = (const u32*)src;
        #pragma unroll
        for (int rep = 0; rep < 8; ++rep){
            int f = rep * 256 + t;
            int c = f >> 5, pu = f & 31;
            xsu[c][pu] = s[(((size_t)b*256 + c0 + c)*16384 + pix0)/2 + pu];
        }
    }
    __syncthreads();
    #pragma unroll
    for (int rep = 0; rep < 2; ++rep){
        int f = rep * 256 + t;                   // 512 = 64 pix x 8 c-groups
        int pix = f >> 3, cu8 = f & 7;
        u32 pk[4];
        #pragma unroll
        for (int d = 0; d < 4; ++d){
            u32 a = xsu[cu8*8 + 2*d][pix >> 1];
            u32 bb = xsu[cu8*8 + 2*d + 1][pix >> 1];
            u16 ha = (pix & 1) ? (u16)(a >> 16) : (u16)(a & 0xffffu);
            u16 hb = (pix & 1) ? (u16)(bb >> 16) : (u16)(bb & 0xffffu);
            pk[d] = (u32)ha | ((u32)hb << 16);
        }
        *(uint4*)(dst + ((size_t)b*16384 + pix0 + pix)*256 + c0 + cu8*8) = *(uint4*)pk;
    }
}

// ---------------- canonicalize weights -> bf16 [o][c] ----------------
__global__ void k_canon_w(const void* __restrict__ wq, const void* __restrict__ wkv,
                          const void* __restrict__ fcw, u16* __restrict__ wb,
                          u16* __restrict__ fcwb, const int* __restrict__ flag){
    const int isf = *flag;
    int i = blockIdx.x * 256 + threadIdx.x;      // 262144 total
    if (i < 196608){
        int o = i >> 8, c = i & 255;
        const void* src = (o < 256) ? wq : wkv;
        int oo = (o < 256) ? o : o - 256;
        float v = isf ? ((const float*)src)[oo*256 + c] : bf2f(((const u16*)src)[oo*256 + c]);
        wb[i] = f2bf(v);
    } else {
        int j = i - 196608;
        float v = isf ? ((const float*)fcw)[j] : bf2f(((const u16*)fcw)[j]);
        fcwb[j] = f2bf(v);
    }
}

// ---------------- canonicalize small tensors -> fp32 ----------------
__global__ void k_canon_f(const void* __restrict__ src, float* __restrict__ dst, int n,
                          const int* __restrict__ flag){
    const int isf = *flag;
    int i = blockIdx.x * 256 + threadIdx.x;
    if (i < n){
        dst[i] = isf ? ((const float*)src)[i] : bf2f(((const u16*)src)[i]);
    }
}

// ---------------- MFMA QKV projection (R13: W tile staged in LDS) ----------------
// R10 structure (32 pix/wave, grid 512 — best measured at 103.8us) with the
// dominant cost removed: every wave re-loaded the 8KB W tile from L2 per ot
// (786 MB of L2 reads, ~200cy latency, only 8 waves/CU to hide it). Now the
// block cooperatively stages W[ot] into LDS once (32B/thread), double-
// buffered so the ot+1 global load flies under ot's MFMAs; af reads become
// ds_read_b128. Row stride 272 u16 (544B) => read slot = 2*l15+quad mod 32,
// mostly 2-way (free, m136). R11/R12 lesson: never duplicate pixel or ot
// ownership — traffic amplification beats occupancy gains.
__global__ __launch_bounds__(256)
void k_proj(const u16* __restrict__ xt, const u16* __restrict__ wb,
            u16* __restrict__ qo, u16* __restrict__ kvo){
    __shared__ __align__(16) u16 wlds[2][16][272];
    const int t = threadIdx.x;
    const int wave = t >> 6, lane = t & 63;
    const int quad = lane >> 4, l15 = lane & 15;
    const int p0 = blockIdx.x * 128 + wave * 32;

    s16x8 bf[2][8];
    #pragma unroll
    for (int nt = 0; nt < 2; ++nt){
        const u16* row = xt + (size_t)(p0 + nt*16 + l15) * 256 + quad * 8;
        #pragma unroll
        for (int kc = 0; kc < 8; ++kc)
            bf[nt][kc] = *(const s16x8*)(row + kc * 32);
    }

    // staging map: thread t covers 32B of the 8KB tile
    const int srow = t >> 4;             // 0..15
    const int scol = (t & 15) * 16;      // u16 units
    {
        const u16* g = wb + srow*256 + scol;
        *(uint4*)&wlds[0][srow][scol]     = *(const uint4*)g;
        *(uint4*)&wlds[0][srow][scol + 8] = *(const uint4*)(g + 8);
    }

    int cur = 0;
    for (int ot = 0; ot < 48; ++ot){
        uint4 pa, pb;
        if (ot < 47){
            const u16* g = wb + (size_t)(ot+1)*4096 + srow*256 + scol;
            pa = *(const uint4*)g;
            pb = *(const uint4*)(g + 8);
        }
        __syncthreads();
        s16x8 af[8];
        {
            const u16* wr = &wlds[cur][l15][quad*8];
            #pragma unroll
            for (int kc = 0; kc < 8; ++kc)
                af[kc] = *(const s16x8*)(wr + kc * 32);
        }
        f32x4 acc0 = {0.f,0.f,0.f,0.f}, acc1 = {0.f,0.f,0.f,0.f};
        #pragma unroll
        for (int kc = 0; kc < 8; ++kc){
            acc0 = __builtin_amdgcn_mfma_f32_16x16x32_bf16(af[kc], bf[0][kc], acc0, 0,0,0);
            acc1 = __builtin_amdgcn_mfma_f32_16x16x32_bf16(af[kc], bf[1][kc], acc1, 0,0,0);
        }
        const int o = ot*16 + quad*4;
        #pragma unroll
        for (int nt = 0; nt < 2; ++nt){
            const f32x4 a = nt ? acc1 : acc0;
            const size_t pix = p0 + nt*16 + l15;
            uint2 st;
            st.x = (u32)f2bf(a[0]) | ((u32)f2bf(a[1]) << 16);
            st.y = (u32)f2bf(a[2]) | ((u32)f2bf(a[3]) << 16);
            if (ot < 16) *(uint2*)(qo  + pix*256 + o)        = st;
            else         *(uint2*)(kvo + pix*512 + (o - 256)) = st;
        }
        if (ot < 47){
            int nb = cur ^ 1;
            *(uint4*)&wlds[nb][srow][scol]     = pa;
            *(uint4*)&wlds[nb][srow][scol + 8] = pb;
            cur = nb;
        }
    }
}

// ---------------- MFMA halo attention (unchanged from R10/R12) ----------------
__global__ __launch_bounds__(512)
void k_attn(const u16* __restrict__ qc, const u16* __restrict__ kvc,
            const float* __restrict__ rh, const float* __restrict__ rw,
            u16* __restrict__ ctx){
    __shared__ __align__(16) u16 kvb[2][15][520];
    __shared__ u16 bht[8][21][64];
    const int t = threadIdx.x;
    const int head = t >> 6, lane = t & 63;
    const int quad = lane >> 4, l15 = lane & 15;
    const int blk = blockIdx.x, b = blockIdx.y;
    const int r0 = (blk >> 4) * 8, c0 = (blk & 15) * 8;

    s16x8 qf[4];
    #pragma unroll
    for (int nt = 0; nt < 4; ++nt){
        int q = nt*16 + l15;
        size_t pix = (size_t)b*16384 + (size_t)(r0 + (q>>3))*128 + (c0 + (q&7));
        qf[nt] = *(const s16x8*)(qc + pix*256 + head*32 + quad*8);
    }

    const int j0 = t >> 6;
    const int ch0 = (t & 63) * 8;

    {   // pre-stage tile 0
        int hh = r0 - 3;
        bool vh = (hh >= 0 && hh < 128);
        int ww0 = c0 - 3 + j0, ww1 = ww0 + 8;
        uint4 v0 = make_uint4(0,0,0,0), v1 = make_uint4(0,0,0,0);
        if (vh && ww0 >= 0 && ww0 < 128)
            v0 = *(const uint4*)(kvc + ((size_t)b*16384 + (size_t)hh*128 + ww0)*512 + ch0);
        if (vh && (j0+8) < 14 && ww1 >= 0 && ww1 < 128)
            v1 = *(const uint4*)(kvc + ((size_t)b*16384 + (size_t)hh*128 + ww1)*512 + ch0);
        *(uint4*)&kvb[0][j0][ch0] = v0;
        if (j0 + 8 < 15) *(uint4*)&kvb[0][j0+8][ch0] = v1;   // rows 8..14; row14 <- zeros
    }

    float bwreg[4][4];
    {
        f32x4 d[2][4];
        #pragma unroll
        for (int mt = 0; mt < 2; ++mt){
            int u = mt*16 + l15;
            s16x8 af;
            #pragma unroll
            for (int i2 = 0; i2 < 8; ++i2) af[i2] = 0;
            if (u <= 26){
                float4 a0 = *(const float4*)(rw + u*32 + quad*8);
                float4 a1 = *(const float4*)(rw + u*32 + quad*8 + 4);
                af[0]=(short)f2bf(a0.x); af[1]=(short)f2bf(a0.y);
                af[2]=(short)f2bf(a0.z); af[3]=(short)f2bf(a0.w);
                af[4]=(short)f2bf(a1.x); af[5]=(short)f2bf(a1.y);
                af[6]=(short)f2bf(a1.z); af[7]=(short)f2bf(a1.w);
            }
            #pragma unroll
            for (int nt = 0; nt < 4; ++nt){
                f32x4 z = {0.f,0.f,0.f,0.f};
                d[mt][nt] = __builtin_amdgcn_mfma_f32_16x16x32_bf16(af, qf[nt], z, 0,0,0);
            }
        }
        #pragma unroll
        for (int mt = 0; mt < 2; ++mt)
            #pragma unroll
            for (int nt = 0; nt < 4; ++nt)
                #pragma unroll
                for (int r = 0; r < 4; ++r){
                    int u = mt*16 + quad*4 + r;
                    if (u >= 6 && u <= 26)
                        bht[head][u-6][nt*16 + l15] = f2bf(d[mt][nt][r] * LOG2E);
                }
        __syncthreads();
        #pragma unroll
        for (int nt = 0; nt < 4; ++nt){
            int q = nt*16 + l15, qy = l15 & 7;
            #pragma unroll
            for (int r = 0; r < 4; ++r){
                int j = quad*4 + r;
                bwreg[nt][r] = (j < 14) ? bf2f(bht[head][j + 7 - qy][q]) : -1e30f;
            }
        }
        __syncthreads();
        #pragma unroll
        for (int mt = 0; mt < 2; ++mt){
            int u = mt*16 + l15;
            s16x8 af;
            #pragma unroll
            for (int i2 = 0; i2 < 8; ++i2) af[i2] = 0;
            if (u <= 26){
                float4 a0 = *(const float4*)(rh + u*32 + quad*8);
                float4 a1 = *(const float4*)(rh + u*32 + quad*8 + 4);
                af[0]=(short)f2bf(a0.x); af[1]=(short)f2bf(a0.y);
                af[2]=(short)f2bf(a0.z); af[3]=(short)f2bf(a0.w);
                af[4]=(short)f2bf(a1.x); af[5]=(short)f2bf(a1.y);
                af[6]=(short)f2bf(a1.z); af[7]=(short)f2bf(a1.w);
            }
            #pragma unroll
            for (int nt = 0; nt < 4; ++nt){
                f32x4 z = {0.f,0.f,0.f,0.f};
                d[mt][nt] = __builtin_amdgcn_mfma_f32_16x16x32_bf16(af, qf[nt], z, 0,0,0);
            }
        }
        #pragma unroll
        for (int mt = 0; mt < 2; ++mt)
            #pragma unroll
            for (int nt = 0; nt < 4; ++nt)
                #pragma unroll
                for (int r = 0; r < 4; ++r){
                    int u = mt*16 + quad*4 + r;
                    if (u >= 6 && u <= 26)
                        bht[head][u-6][nt*16 + l15] = f2bf(d[mt][nt][r] * LOG2E);
                }
    }

    const int krow = (l15 < 15) ? l15 : 14;   // clamped K row (row14 == zeros)

    float m_[4] = {-1e30f,-1e30f,-1e30f,-1e30f};
    float l_[4] = {0.f,0.f,0.f,0.f};
    f32x4 O[2][4];
    #pragma unroll
    for (int mt = 0; mt < 2; ++mt)
        #pragma unroll
        for (int nt = 0; nt < 4; ++nt){ f32x4 z = {0.f,0.f,0.f,0.f}; O[mt][nt] = z; }

    #pragma unroll 2
    for (int tile = 0; tile < 14; ++tile){
        uint4 p0 = make_uint4(0,0,0,0), p1 = make_uint4(0,0,0,0);
        if (tile < 13){
            int hh = r0 - 3 + tile + 1;
            bool vh = (hh >= 0 && hh < 128);
            int ww0 = c0 - 3 + j0, ww1 = ww0 + 8;
            if (vh && ww0 >= 0 && ww0 < 128)
                p0 = *(const uint4*)(kvc + ((size_t)b*16384 + (size_t)hh*128 + ww0)*512 + ch0);
            if (vh && (j0+8) < 14 && ww1 >= 0 && ww1 < 128)
                p1 = *(const uint4*)(kvc + ((size_t)b*16384 + (size_t)hh*128 + ww1)*512 + ch0);
        }
        __syncthreads();
        const u16* kb = &kvb[tile & 1][0][0];

        s16x8 ak = *(const s16x8*)(kb + krow*520 + head*32 + quad*8);
        f32x4 sc[4];
        #pragma unroll
        for (int nt = 0; nt < 4; ++nt){
            f32x4 z = {0.f,0.f,0.f,0.f};
            sc[nt] = __builtin_amdgcn_mfma_f32_16x16x32_bf16(ak, qf[nt], z, 0,0,0);
        }
        s16x4 av[2];
        #pragma unroll
        for (int mt = 0; mt < 2; ++mt)
            #pragma unroll
            for (int i = 0; i < 4; ++i){
                int vr = quad*4 + i; vr = (vr < 15) ? vr : 14;   // row14 == zeros
                av[mt][i] = (short)kb[vr*520 + 256 + head*32 + mt*16 + l15];
            }

        #pragma unroll
        for (int nt = 0; nt < 4; ++nt){
            int q = nt*16 + l15;
            int qx = q >> 3;
            float bh = bf2f(bht[head][tile + 7 - qx][q]);
            float s0 = fmaf(sc[nt][0], QS2, bwreg[nt][0] + bh);
            float s1 = fmaf(sc[nt][1], QS2, bwreg[nt][1] + bh);
            float s2 = fmaf(sc[nt][2], QS2, bwreg[nt][2] + bh);
            float s3 = fmaf(sc[nt][3], QS2, bwreg[nt][3] + bh);
            float mx = fmaxf(fmaxf(s0, s1), fmaxf(s2, s3));
            mx = fmaxf(mx, __shfl_xor(mx, 16));
            mx = fmaxf(mx, __shfl_xor(mx, 32));
            float mn = fmaxf(m_[nt], mx);
            float al = exp2fast(m_[nt] - mn);
            m_[nt] = mn;
            float e0 = exp2fast(s0 - mn), e1 = exp2fast(s1 - mn);
            float e2 = exp2fast(s2 - mn), e3 = exp2fast(s3 - mn);
            l_[nt] = l_[nt] * al + ((e0 + e1) + (e2 + e3));   // per-lane partial
            s16x4 pp;
            pp[0] = (short)f2bf(e0); pp[1] = (short)f2bf(e1);
            pp[2] = (short)f2bf(e2); pp[3] = (short)f2bf(e3);
            #pragma unroll
            for (int mt = 0; mt < 2; ++mt){
                f32x4 o = O[mt][nt];
                o[0] *= al; o[1] *= al; o[2] *= al; o[3] *= al;
                O[mt][nt] = mfma16(av[mt], pp, o);
            }
        }
        if (tile < 13){
            int nb = (tile + 1) & 1;
            *(uint4*)&kvb[nb][j0][ch0] = p0;
            if (j0 + 8 < 15) *(uint4*)&kvb[nb][j0+8][ch0] = p1;   // row14 <- zeros
        }
    }

    #pragma unroll
    for (int nt = 0; nt < 4; ++nt){
        float l = l_[nt];
        l += __shfl_xor(l, 16);
        l += __shfl_xor(l, 32);
        float inv = 1.f / l;
        int q = nt*16 + l15;
        size_t base = (((size_t)(b*256 + blk))*64 + q)*256 + head*32 + quad*4;
        #pragma unroll
        for (int mt = 0; mt < 2; ++mt){
            f32x4 o = O[mt][nt];
            u32 w0 = (u32)f2bf(o[0]*inv) | ((u32)f2bf(o[1]*inv) << 16);
            u32 w1 = (u32)f2bf(o[2]*inv) | ((u32)f2bf(o[3]*inv) << 16);
            uint2 st; st.x = w0; st.y = w1;
            *(uint2*)(ctx + base + mt*16) = st;
        }
    }
}

// ---------------- MFMA output projection + bias (R13: fcw tile in LDS) ----------------
// Same staging fix as k_proj: R10 structure (32 pix/wave, grid 512), fcw
// tile (8KB) staged per block per ot, double-buffered.
__global__ __launch_bounds__(256)
void k_out(const u16* __restrict__ ctx, const u16* __restrict__ fcwb,
           const float* __restrict__ fcb, void* __restrict__ outp,
           const int* __restrict__ flag){
    __shared__ __align__(16) u16 wlds[2][16][272];
    const int t = threadIdx.x;
    const int wave = t >> 6, lane = t & 63;
    const int quad = lane >> 4, l15 = lane & 15;
    const int p0 = blockIdx.x * 128 + wave * 32;
    const int b = p0 >> 14;
    const int h = (p0 >> 7) & 127, w0 = p0 & 127;
    const int isf32 = *flag;

    s16x8 af[2][8];
    #pragma unroll
    for (int mt = 0; mt < 2; ++mt){
        int w = w0 + mt*16 + l15;
        int blkid = (h >> 3) * 16 + (w >> 3);
        int qi = (h & 7) * 8 + (w & 7);
        const u16* row = ctx + ((size_t)(b*256 + blkid)*64 + qi) * 256 + quad * 8;
        #pragma unroll
        for (int kc = 0; kc < 8; ++kc)
            af[mt][kc] = *(const s16x8*)(row + kc * 32);
    }

    const int srow = t >> 4;
    const int scol = (t & 15) * 16;
    {
        const u16* g = fcwb + srow*256 + scol;
        *(uint4*)&wlds[0][srow][scol]     = *(const uint4*)g;
        *(uint4*)&wlds[0][srow][scol + 8] = *(const uint4*)(g + 8);
    }

    int cur = 0;
    for (int ot = 0; ot < 16; ++ot){
        uint4 pa, pb;
        if (ot < 15){
            const u16* g = fcwb + (size_t)(ot+1)*4096 + srow*256 + scol;
            pa = *(const uint4*)g;
            pb = *(const uint4*)(g + 8);
        }
        __syncthreads();
        s16x8 bfr[8];
        {
            const u16* wr = &wlds[cur][l15][quad*8];
            #pragma unroll
            for (int kc = 0; kc < 8; ++kc)
                bfr[kc] = *(const s16x8*)(wr + kc * 32);
        }
        f32x4 acc0 = {0.f,0.f,0.f,0.f}, acc1 = {0.f,0.f,0.f,0.f};
        #pragma unroll
        for (int kc = 0; kc < 8; ++kc){
            acc0 = __builtin_amdgcn_mfma_f32_16x16x32_bf16(af[0][kc], bfr[kc], acc0, 0,0,0);
            acc1 = __builtin_amdgcn_mfma_f32_16x16x32_bf16(af[1][kc], bfr[kc], acc1, 0,0,0);
        }
        const float bias = fcb[ot*16 + l15];
        #pragma unroll
        for (int mt = 0; mt < 2; ++mt){
            const f32x4 a = mt ? acc1 : acc0;
            const int wv = w0 + mt*16 + quad*4;
            const size_t obase = (size_t)b*4194304 + (size_t)(ot*16 + l15)*16384
                               + (size_t)h*128 + wv;
            if (isf32){
                float4 v;
                v.x = a[0] + bias; v.y = a[1] + bias;
                v.z = a[2] + bias; v.w = a[3] + bias;
                *(float4*)((float*)outp + obase) = v;
            } else {
                uint2 v;
                v.x = (u32)f2bf(a[0] + bias) | ((u32)f2bf(a[1] + bias) << 16);
                v.y = (u32)f2bf(a[2] + bias) | ((u32)f2bf(a[3] + bias) << 16);
                *(uint2*)((u16*)outp + obase) = v;
            }
        }
        if (ot < 15){
            int nb = cur ^ 1;
            *(uint4*)&wlds[nb][srow][scol]     = pa;
            *(uint4*)&wlds[nb][srow][scol + 8] = pb;
            cur = nb;
        }
    }
}

extern "C" void kernel_launch(void* const* d_in, const int* in_sizes, int n_in,
                              void* d_out, int out_size, void* d_ws, size_t ws_size,
                              hipStream_t stream){
    const void* x    = d_in[0];
    const void* wq   = d_in[1];
    const void* wkv  = d_in[2];
    const void* fcw  = d_in[3];
    const void* fcb  = d_in[4];
    const void* relh = d_in[5];
    const void* relw = d_in[6];

    char* ws = (char*)d_ws;
    u16*   xt   = (u16*)(ws + WS_XT);
    u16*   wb   = (u16*)(ws + WS_WB);
    u16*   fcwb = (u16*)(ws + WS_FCWB);
    float* fcbf = (float*)(ws + WS_FCB);
    float* rhf  = (float*)(ws + WS_RH);
    float* rwf  = (float*)(ws + WS_RW);
    int*   flag = (int*)(ws + WS_FLAG);
    u16*   qb   = (u16*)(ws + WS_Q);
    u16*   kvb  = (u16*)(ws + WS_KV);
    u16*   ctxb = (u16*)(ws + WS_CTX);

    k_detect<<<1, 64, 0, stream>>>((const u16*)x, flag);
    k_canon_xt<<<4096, 256, 0, stream>>>(x, xt, flag);
    k_canon_w<<<1024, 256, 0, stream>>>(wq, wkv, fcw, wb, fcwb, flag);
    k_canon_f<<<1, 256, 0, stream>>>(fcb,  fcbf, 256, flag);
    k_canon_f<<<4, 256, 0, stream>>>(relh, rhf,  864, flag);
    k_canon_f<<<4, 256, 0, stream>>>(relw, rwf,  864, flag);

    k_proj<<<512, 256, 0, stream>>>(xt, wb, qb, kvb);
    dim3 ga(256, 4);
    k_attn<<<ga, 512, 0, stream>>>(qb, kvb, rhf, rwf, ctxb);
    k_out<<<512, 256, 0, stream>>>(ctxb, fcwb, fcbf, d_out, flag);
}

// Round 10
// 294.176 us; speedup vs baseline: 1.6266x; 1.0223x over previous
//
#include <hip/hip_runtime.h>
#include <hip/hip_bf16.h>
#include <stdint.h>

typedef unsigned short u16;
typedef unsigned int u32;

// ---- problem constants ----
#define HEADS  8
#define DH     32
#define BLK    8
#define HALO   3
#define WINSZ  14
#define QKSCALE 0.17677669529663689f   // 32^-0.5
#define LOG2E   1.4426950408889634f
#define QS2     (QKSCALE * LOG2E)      // scores in log2 domain
#define DEFER_THR 10.0f                // skip rescale while max growth < 2^10

// ---- workspace layout (bytes) ----
#define WS_XT   ((size_t)0)                    // xt bf16 [B*16384][256]: 33,554,432
#define WS_WB   ((size_t)33554432)             // w bf16 [768][256] (q,k,v): 393,216
#define WS_FCWB (WS_WB + 393216)               // fc_w bf16 [256][256]: 131,072
#define WS_FCB  (WS_FCWB + 131072)             // fc_b fp32: 1,024
#define WS_RH   (WS_FCB + 1024)                // rel_h fp32: 3,456
#define WS_RW   (WS_RH + 3456)                 // rel_w fp32: 3,456
#define WS_FLAG (WS_RW + 3456)                 // int flag
#define WS_Q    ((size_t)34611200)             // q bf16 [65536][256]: 33,554,432
#define WS_KV   (WS_Q + 33554432)              // kv bf16 [65536][512]: 67,108,864
#define WS_CTX  (WS_KV + 67108864)             // ctx bf16 [B*256 blk][64][256]: 33,554,432

typedef float f32x4 __attribute__((ext_vector_type(4)));
typedef short s16x8 __attribute__((ext_vector_type(8)));
typedef short s16x4 __attribute__((ext_vector_type(4)));

__device__ __forceinline__ float bflo(u32 u){ return __uint_as_float(u << 16); }
__device__ __forceinline__ float bfhi(u32 u){ return __uint_as_float(u & 0xffff0000u); }
__device__ __forceinline__ float bf2f(u16 h){ return __uint_as_float(((u32)h) << 16); }
__device__ __forceinline__ u16 f2bf(float f){
    u32 u = __float_as_uint(f);
    u32 r = (u + 0x7fffu + ((u >> 16) & 1u)) >> 16;   // RNE
    return (u16)r;
}
// m240-approved path: scalar cast, compiler lowers/fuses (NOT inline asm).
__device__ __forceinline__ u16 f2bf_c(float f){
    __hip_bfloat16 h = __float2bfloat16(f);
    return __builtin_bit_cast(u16, h);
}

// NOTE: __has_builtin guards on amdgcn builtins must live inside
// __HIP_DEVICE_COMPILE__ — host pass picks the wrong branch otherwise (R3).
#if defined(__HIP_DEVICE_COMPILE__)
__device__ __forceinline__ f32x4 mfma16(s16x4 a, s16x4 b, f32x4 c){
    return __builtin_amdgcn_mfma_f32_16x16x16bf16_1k(a, b, c, 0, 0, 0);
}
#else
__device__ __forceinline__ f32x4 mfma16(s16x4 a, s16x4 b, f32x4 c){ return c; }
#endif

#if defined(__HIP_DEVICE_COMPILE__) && __has_builtin(__builtin_amdgcn_exp2f)
__device__ __forceinline__ float exp2fast(float x){ return __builtin_amdgcn_exp2f(x); }
#else
__device__ __forceinline__ float exp2fast(float x){ return exp2f(x); }
#endif

// ---------------- dtype detector ----------------
__global__ void k_detect(const u16* __restrict__ x, int* __restrict__ flag){
    int t = threadIdx.x;
    int wild = 0;
    for (int i = t; i < 1024; i += 64){
        u16 u = x[2*i];
        int ef = (u >> 7) & 0xff;
        if (ef >= 0x90) wild = 1;
    }
    int any = __any(wild);
    if (t == 0) *flag = any ? 1 : 0;
}

// ---------------- canonicalize + transpose x -> xt[pix][c] bf16 ----------------
// tile: 64 c x 64 pix per block via LDS
__global__ __launch_bounds__(256)
void k_canon_xt(const void* __restrict__ src, u16* __restrict__ dst,
                const int* __restrict__ flag){
    __shared__ u32 xsu[64][33];
    const int tile = blockIdx.x;                 // [b(4)][ct(4)][pt(256)]
    const int pt = tile & 255, ct = (tile >> 8) & 3, b = tile >> 10;
    const int pix0 = pt * 64, c0 = ct * 64;
    const int t = threadIdx.x;
    const int isf = *flag;
    if (isf){
        const float* s = (const float*)src;
        #pragma unroll
        for (int rep = 0; rep < 8; ++rep){
            int f = rep * 256 + t;
            int c = f >> 5, pu = f & 31;
            const float2 v = *(const float2*)(s + ((size_t)b*256 + c0 + c)*16384 + pix0 + pu*2);
            xsu[c][pu] = (u32)f2bf(v.x) | ((u32)f2bf(v.y) << 16);
        }
    } else {
        const u32* s = (const u32*)src;
        #pragma unroll
        for (int rep = 0; rep < 8; ++rep){
            int f = rep * 256 + t;
            int c = f >> 5, pu = f & 31;
            xsu[c][pu] = s[(((size_t)b*256 + c0 + c)*16384 + pix0)/2 + pu];
        }
    }
    __syncthreads();
    #pragma unroll
    for (int rep = 0; rep < 2; ++rep){
        int f = rep * 256 + t;                   // 512 = 64 pix x 8 c-groups
        int pix = f >> 3, cu8 = f & 7;
        u32 pk[4];
        #pragma unroll
        for (int d = 0; d < 4; ++d){
            u32 a = xsu[cu8*8 + 2*d][pix >> 1];
            u32 bb = xsu[cu8*8 + 2*d + 1][pix >> 1];
            u16 ha = (pix & 1) ? (u16)(a >> 16) : (u16)(a & 0xffffu);
            u16 hb = (pix & 1) ? (u16)(bb >> 16) : (u16)(bb & 0xffffu);
            pk[d] = (u32)ha | ((u32)hb << 16);
        }
        *(uint4*)(dst + ((size_t)b*16384 + pix0 + pix)*256 + c0 + cu8*8) = *(uint4*)pk;
    }
}

// ---------------- canonicalize weights -> bf16 [o][c] ----------------
__global__ void k_canon_w(const void* __restrict__ wq, const void* __restrict__ wkv,
                          const void* __restrict__ fcw, u16* __restrict__ wb,
                          u16* __restrict__ fcwb, const int* __restrict__ flag){
    const int isf = *flag;
    int i = blockIdx.x * 256 + threadIdx.x;      // 262144 total
    if (i < 196608){
        int o = i >> 8, c = i & 255;
        const void* src = (o < 256) ? wq : wkv;
        int oo = (o < 256) ? o : o - 256;
        float v = isf ? ((const float*)src)[oo*256 + c] : bf2f(((const u16*)src)[oo*256 + c]);
        wb[i] = f2bf(v);
    } else {
        int j = i - 196608;
        float v = isf ? ((const float*)fcw)[j] : bf2f(((const u16*)fcw)[j]);
        fcwb[j] = f2bf(v);
    }
}

// ---------------- canonicalize small tensors -> fp32 ----------------
__global__ void k_canon_f(const void* __restrict__ src, float* __restrict__ dst, int n,
                          const int* __restrict__ flag){
    const int isf = *flag;
    int i = blockIdx.x * 256 + threadIdx.x;
    if (i < n){
        dst[i] = isf ? ((const float*)src)[i] : bf2f(((const u16*)src)[i]);
    }
}

// ---------------- MFMA QKV projection (R13: W tile staged in LDS) ----------------
__global__ __launch_bounds__(256)
void k_proj(const u16* __restrict__ xt, const u16* __restrict__ wb,
            u16* __restrict__ qo, u16* __restrict__ kvo){
    __shared__ __align__(16) u16 wlds[2][16][272];
    const int t = threadIdx.x;
    const int wave = t >> 6, lane = t & 63;
    const int quad = lane >> 4, l15 = lane & 15;
    const int p0 = blockIdx.x * 128 + wave * 32;

    s16x8 bf[2][8];
    #pragma unroll
    for (int nt = 0; nt < 2; ++nt){
        const u16* row = xt + (size_t)(p0 + nt*16 + l15) * 256 + quad * 8;
        #pragma unroll
        for (int kc = 0; kc < 8; ++kc)
            bf[nt][kc] = *(const s16x8*)(row + kc * 32);
    }

    // staging map: thread t covers 32B of the 8KB tile
    const int srow = t >> 4;             // 0..15
    const int scol = (t & 15) * 16;      // u16 units
    {
        const u16* g = wb + srow*256 + scol;
        *(uint4*)&wlds[0][srow][scol]     = *(const uint4*)g;
        *(uint4*)&wlds[0][srow][scol + 8] = *(const uint4*)(g + 8);
    }

    int cur = 0;
    for (int ot = 0; ot < 48; ++ot){
        uint4 pa, pb;
        if (ot < 47){
            const u16* g = wb + (size_t)(ot+1)*4096 + srow*256 + scol;
            pa = *(const uint4*)g;
            pb = *(const uint4*)(g + 8);
        }
        __syncthreads();
        s16x8 af[8];
        {
            const u16* wr = &wlds[cur][l15][quad*8];
            #pragma unroll
            for (int kc = 0; kc < 8; ++kc)
                af[kc] = *(const s16x8*)(wr + kc * 32);
        }
        f32x4 acc0 = {0.f,0.f,0.f,0.f}, acc1 = {0.f,0.f,0.f,0.f};
        #pragma unroll
        for (int kc = 0; kc < 8; ++kc){
            acc0 = __builtin_amdgcn_mfma_f32_16x16x32_bf16(af[kc], bf[0][kc], acc0, 0,0,0);
            acc1 = __builtin_amdgcn_mfma_f32_16x16x32_bf16(af[kc], bf[1][kc], acc1, 0,0,0);
        }
        const int o = ot*16 + quad*4;
        #pragma unroll
        for (int nt = 0; nt < 2; ++nt){
            const f32x4 a = nt ? acc1 : acc0;
            const size_t pix = p0 + nt*16 + l15;
            uint2 st;
            st.x = (u32)f2bf(a[0]) | ((u32)f2bf(a[1]) << 16);
            st.y = (u32)f2bf(a[2]) | ((u32)f2bf(a[3]) << 16);
            if (ot < 16) *(uint2*)(qo  + pix*256 + o)        = st;
            else         *(uint2*)(kvo + pix*512 + (o - 256)) = st;
        }
        if (ot < 47){
            int nb = cur ^ 1;
            *(uint4*)&wlds[nb][srow][scol]     = pa;
            *(uint4*)&wlds[nb][srow][scol + 8] = pb;
            cur = nb;
        }
    }
}

// ---------------- MFMA halo attention (R14 = R13 + defer-max + cast-pack) ----------------
// VALU-bound (R13 PMC: VALUBusy 52%, MfmaUtil 10%). Two inner-loop cuts:
//  * defer-max (T13): skip max-shuffles + O/l rescale while per-lane max
//    growth < 2^DEFER_THR. Wave-uniform __all decision; skip path keeps
//    m_old so P <= 2^10 (bf16-safe); tile 0 always takes the full path.
//    (Excluded in R10 on suspicion — bisect convicted the cvt_pk ASM, not
//    this; the asm is NOT used here.)
//  * P packing via __float2bfloat16 scalar casts (m240: compiler-lowered
//    cast beats both manual RNE bit-ops and inline-asm cvt_pk).
__global__ __launch_bounds__(512)
void k_attn(const u16* __restrict__ qc, const u16* __restrict__ kvc,
            const float* __restrict__ rh, const float* __restrict__ rw,
            u16* __restrict__ ctx){
    __shared__ __align__(16) u16 kvb[2][15][520];
    __shared__ u16 bht[8][21][64];
    const int t = threadIdx.x;
    const int head = t >> 6, lane = t & 63;
    const int quad = lane >> 4, l15 = lane & 15;
    const int blk = blockIdx.x, b = blockIdx.y;
    const int r0 = (blk >> 4) * 8, c0 = (blk & 15) * 8;

    s16x8 qf[4];
    #pragma unroll
    for (int nt = 0; nt < 4; ++nt){
        int q = nt*16 + l15;
        size_t pix = (size_t)b*16384 + (size_t)(r0 + (q>>3))*128 + (c0 + (q&7));
        qf[nt] = *(const s16x8*)(qc + pix*256 + head*32 + quad*8);
    }

    const int j0 = t >> 6;
    const int ch0 = (t & 63) * 8;

    {   // pre-stage tile 0
        int hh = r0 - 3;
        bool vh = (hh >= 0 && hh < 128);
        int ww0 = c0 - 3 + j0, ww1 = ww0 + 8;
        uint4 v0 = make_uint4(0,0,0,0), v1 = make_uint4(0,0,0,0);
        if (vh && ww0 >= 0 && ww0 < 128)
            v0 = *(const uint4*)(kvc + ((size_t)b*16384 + (size_t)hh*128 + ww0)*512 + ch0);
        if (vh && (j0+8) < 14 && ww1 >= 0 && ww1 < 128)
            v1 = *(const uint4*)(kvc + ((size_t)b*16384 + (size_t)hh*128 + ww1)*512 + ch0);
        *(uint4*)&kvb[0][j0][ch0] = v0;
        if (j0 + 8 < 15) *(uint4*)&kvb[0][j0+8][ch0] = v1;   // rows 8..14; row14 <- zeros
    }

    float bwreg[4][4];
    {
        f32x4 d[2][4];
        #pragma unroll
        for (int mt = 0; mt < 2; ++mt){
            int u = mt*16 + l15;
            s16x8 af;
            #pragma unroll
            for (int i2 = 0; i2 < 8; ++i2) af[i2] = 0;
            if (u <= 26){
                float4 a0 = *(const float4*)(rw + u*32 + quad*8);
                float4 a1 = *(const float4*)(rw + u*32 + quad*8 + 4);
                af[0]=(short)f2bf(a0.x); af[1]=(short)f2bf(a0.y);
                af[2]=(short)f2bf(a0.z); af[3]=(short)f2bf(a0.w);
                af[4]=(short)f2bf(a1.x); af[5]=(short)f2bf(a1.y);
                af[6]=(short)f2bf(a1.z); af[7]=(short)f2bf(a1.w);
            }
            #pragma unroll
            for (int nt = 0; nt < 4; ++nt){
                f32x4 z = {0.f,0.f,0.f,0.f};
                d[mt][nt] = __builtin_amdgcn_mfma_f32_16x16x32_bf16(af, qf[nt], z, 0,0,0);
            }
        }
        #pragma unroll
        for (int mt = 0; mt < 2; ++mt)
            #pragma unroll
            for (int nt = 0; nt < 4; ++nt)
                #pragma unroll
                for (int r = 0; r < 4; ++r){
                    int u = mt*16 + quad*4 + r;
                    if (u >= 6 && u <= 26)
                        bht[head][u-6][nt*16 + l15] = f2bf(d[mt][nt][r] * LOG2E);
                }
        __syncthreads();
        #pragma unroll
        for (int nt = 0; nt < 4; ++nt){
            int q = nt*16 + l15, qy = l15 & 7;
            #pragma unroll
            for (int r = 0; r < 4; ++r){
                int j = quad*4 + r;
                bwreg[nt][r] = (j < 14) ? bf2f(bht[head][j + 7 - qy][q]) : -1e30f;
            }
        }
        __syncthreads();
        #pragma unroll
        for (int mt = 0; mt < 2; ++mt){
            int u = mt*16 + l15;
            s16x8 af;
            #pragma unroll
            for (int i2 = 0; i2 < 8; ++i2) af[i2] = 0;
            if (u <= 26){
                float4 a0 = *(const float4*)(rh + u*32 + quad*8);
                float4 a1 = *(const float4*)(rh + u*32 + quad*8 + 4);
                af[0]=(short)f2bf(a0.x); af[1]=(short)f2bf(a0.y);
                af[2]=(short)f2bf(a0.z); af[3]=(short)f2bf(a0.w);
                af[4]=(short)f2bf(a1.x); af[5]=(short)f2bf(a1.y);
                af[6]=(short)f2bf(a1.z); af[7]=(short)f2bf(a1.w);
            }
            #pragma unroll
            for (int nt = 0; nt < 4; ++nt){
                f32x4 z = {0.f,0.f,0.f,0.f};
                d[mt][nt] = __builtin_amdgcn_mfma_f32_16x16x32_bf16(af, qf[nt], z, 0,0,0);
            }
        }
        #pragma unroll
        for (int mt = 0; mt < 2; ++mt)
            #pragma unroll
            for (int nt = 0; nt < 4; ++nt)
                #pragma unroll
                for (int r = 0; r < 4; ++r){
                    int u = mt*16 + quad*4 + r;
                    if (u >= 6 && u <= 26)
                        bht[head][u-6][nt*16 + l15] = f2bf(d[mt][nt][r] * LOG2E);
                }
    }

    const int krow = (l15 < 15) ? l15 : 14;   // clamped K row (row14 == zeros)

    float m_[4] = {-1e30f,-1e30f,-1e30f,-1e30f};
    float l_[4] = {0.f,0.f,0.f,0.f};
    f32x4 O[2][4];
    #pragma unroll
    for (int mt = 0; mt < 2; ++mt)
        #pragma unroll
        for (int nt = 0; nt < 4; ++nt){ f32x4 z = {0.f,0.f,0.f,0.f}; O[mt][nt] = z; }

    #pragma unroll 2
    for (int tile = 0; tile < 14; ++tile){
        uint4 p0 = make_uint4(0,0,0,0), p1 = make_uint4(0,0,0,0);
        if (tile < 13){
            int hh = r0 - 3 + tile + 1;
            bool vh = (hh >= 0 && hh < 128);
            int ww0 = c0 - 3 + j0, ww1 = ww0 + 8;
            if (vh && ww0 >= 0 && ww0 < 128)
                p0 = *(const uint4*)(kvc + ((size_t)b*16384 + (size_t)hh*128 + ww0)*512 + ch0);
            if (vh && (j0+8) < 14 && ww1 >= 0 && ww1 < 128)
                p1 = *(const uint4*)(kvc + ((size_t)b*16384 + (size_t)hh*128 + ww1)*512 + ch0);
        }
        __syncthreads();
        const u16* kb = &kvb[tile & 1][0][0];

        s16x8 ak = *(const s16x8*)(kb + krow*520 + head*32 + quad*8);
        f32x4 sc[4];
        #pragma unroll
        for (int nt = 0; nt < 4; ++nt){
            f32x4 z = {0.f,0.f,0.f,0.f};
            sc[nt] = __builtin_amdgcn_mfma_f32_16x16x32_bf16(ak, qf[nt], z, 0,0,0);
        }
        s16x4 av[2];
        #pragma unroll
        for (int mt = 0; mt < 2; ++mt)
            #pragma unroll
            for (int i = 0; i < 4; ++i){
                int vr = quad*4 + i; vr = (vr < 15) ? vr : 14;   // row14 == zeros
                av[mt][i] = (short)kb[vr*520 + 256 + head*32 + mt*16 + l15];
            }

        #pragma unroll
        for (int nt = 0; nt < 4; ++nt){
            int q = nt*16 + l15;
            int qx = q >> 3;
            float bh = bf2f(bht[head][tile + 7 - qx][q]);
            float s0 = fmaf(sc[nt][0], QS2, bwreg[nt][0] + bh);
            float s1 = fmaf(sc[nt][1], QS2, bwreg[nt][1] + bh);
            float s2 = fmaf(sc[nt][2], QS2, bwreg[nt][2] + bh);
            float s3 = fmaf(sc[nt][3], QS2, bwreg[nt][3] + bh);
            float mx4 = fmaxf(fmaxf(s0, s1), fmaxf(s2, s3));
            if (!__all(mx4 <= m_[nt] + DEFER_THR)){
                float mx = fmaxf(mx4, __shfl_xor(mx4, 16));
                mx = fmaxf(mx, __shfl_xor(mx, 32));
                float mn = fmaxf(m_[nt], mx);
                float al = exp2fast(m_[nt] - mn);
                m_[nt] = mn;
                l_[nt] *= al;
                #pragma unroll
                for (int mt = 0; mt < 2; ++mt){
                    O[mt][nt][0] *= al; O[mt][nt][1] *= al;
                    O[mt][nt][2] *= al; O[mt][nt][3] *= al;
                }
            }
            float e0 = exp2fast(s0 - m_[nt]), e1 = exp2fast(s1 - m_[nt]);
            float e2 = exp2fast(s2 - m_[nt]), e3 = exp2fast(s3 - m_[nt]);
            l_[nt] += (e0 + e1) + (e2 + e3);   // per-lane partial
            s16x4 pp;
            pp[0] = (short)f2bf_c(e0); pp[1] = (short)f2bf_c(e1);
            pp[2] = (short)f2bf_c(e2); pp[3] = (short)f2bf_c(e3);
            #pragma unroll
            for (int mt = 0; mt < 2; ++mt)
                O[mt][nt] = mfma16(av[mt], pp, O[mt][nt]);
        }
        if (tile < 13){
            int nb = (tile + 1) & 1;
            *(uint4*)&kvb[nb][j0][ch0] = p0;
            if (j0 + 8 < 15) *(uint4*)&kvb[nb][j0+8][ch0] = p1;   // row14 <- zeros
        }
    }

    #pragma unroll
    for (int nt = 0; nt < 4; ++nt){
        float l = l_[nt];
        l += __shfl_xor(l, 16);
        l += __shfl_xor(l, 32);
        float inv = 1.f / l;
        int q = nt*16 + l15;
        size_t base = (((size_t)(b*256 + blk))*64 + q)*256 + head*32 + quad*4;
        #pragma unroll
        for (int mt = 0; mt < 2; ++mt){
            f32x4 o = O[mt][nt];
            u32 w0 = (u32)f2bf(o[0]*inv) | ((u32)f2bf(o[1]*inv) << 16);
            u32 w1 = (u32)f2bf(o[2]*inv) | ((u32)f2bf(o[3]*inv) << 16);
            uint2 st; st.x = w0; st.y = w1;
            *(uint2*)(ctx + base + mt*16) = st;
        }
    }
}

// ---------------- MFMA output projection + bias (R13: fcw tile in LDS) ----------------
__global__ __launch_bounds__(256)
void k_out(const u16* __restrict__ ctx, const u16* __restrict__ fcwb,
           const float* __restrict__ fcb, void* __restrict__ outp,
           const int* __restrict__ flag){
    __shared__ __align__(16) u16 wlds[2][16][272];
    const int t = threadIdx.x;
    const int wave = t >> 6, lane = t & 63;
    const int quad = lane >> 4, l15 = lane & 15;
    const int p0 = blockIdx.x * 128 + wave * 32;
    const int b = p0 >> 14;
    const int h = (p0 >> 7) & 127, w0 = p0 & 127;
    const int isf32 = *flag;

    s16x8 af[2][8];
    #pragma unroll
    for (int mt = 0; mt < 2; ++mt){
        int w = w0 + mt*16 + l15;
        int blkid = (h >> 3) * 16 + (w >> 3);
        int qi = (h & 7) * 8 + (w & 7);
        const u16* row = ctx + ((size_t)(b*256 + blkid)*64 + qi) * 256 + quad * 8;
        #pragma unroll
        for (int kc = 0; kc < 8; ++kc)
            af[mt][kc] = *(const s16x8*)(row + kc * 32);
    }

    const int srow = t >> 4;
    const int scol = (t & 15) * 16;
    {
        const u16* g = fcwb + srow*256 + scol;
        *(uint4*)&wlds[0][srow][scol]     = *(const uint4*)g;
        *(uint4*)&wlds[0][srow][scol + 8] = *(const uint4*)(g + 8);
    }

    int cur = 0;
    for (int ot = 0; ot < 16; ++ot){
        uint4 pa, pb;
        if (ot < 15){
            const u16* g = fcwb + (size_t)(ot+1)*4096 + srow*256 + scol;
            pa = *(const uint4*)g;
            pb = *(const uint4*)(g + 8);
        }
        __syncthreads();
        s16x8 bfr[8];
        {
            const u16* wr = &wlds[cur][l15][quad*8];
            #pragma unroll
            for (int kc = 0; kc < 8; ++kc)
                bfr[kc] = *(const s16x8*)(wr + kc * 32);
        }
        f32x4 acc0 = {0.f,0.f,0.f,0.f}, acc1 = {0.f,0.f,0.f,0.f};
        #pragma unroll
        for (int kc = 0; kc < 8; ++kc){
            acc0 = __builtin_amdgcn_mfma_f32_16x16x32_bf16(af[0][kc], bfr[kc], acc0, 0,0,0);
            acc1 = __builtin_amdgcn_mfma_f32_16x16x32_bf16(af[1][kc], bfr[kc], acc1, 0,0,0);
        }
        const float bias = fcb[ot*16 + l15];
        #pragma unroll
        for (int mt = 0; mt < 2; ++mt){
            const f32x4 a = mt ? acc1 : acc0;
            const int wv = w0 + mt*16 + quad*4;
            const size_t obase = (size_t)b*4194304 + (size_t)(ot*16 + l15)*16384
                               + (size_t)h*128 + wv;
            if (isf32){
                float4 v;
                v.x = a[0] + bias; v.y = a[1] + bias;
                v.z = a[2] + bias; v.w = a[3] + bias;
                *(float4*)((float*)outp + obase) = v;
            } else {
                uint2 v;
                v.x = (u32)f2bf(a[0] + bias) | ((u32)f2bf(a[1] + bias) << 16);
                v.y = (u32)f2bf(a[2] + bias) | ((u32)f2bf(a[3] + bias) << 16);
                *(uint2*)((u16*)outp + obase) = v;
            }
        }
        if (ot < 15){
            int nb = cur ^ 1;
            *(uint4*)&wlds[nb][srow][scol]     = pa;
            *(uint4*)&wlds[nb][srow][scol + 8] = pb;
            cur = nb;
        }
    }
}

extern "C" void kernel_launch(void* const* d_in, const int* in_sizes, int n_in,
                              void* d_out, int out_size, void* d_ws, size_t ws_size,
                              hipStream_t stream){
    const void* x    = d_in[0];
    const void* wq   = d_in[1];
    const void* wkv  = d_in[2];
    const void* fcw  = d_in[3];
    const void* fcb  = d_in[4];
    const void* relh = d_in[5];
    const void* relw = d_in[6];

    char* ws = (char*)d_ws;
    u16*   xt   = (u16*)(ws + WS_XT);
    u16*   wb   = (u16*)(ws + WS_WB);
    u16*   fcwb = (u16*)(ws + WS_FCWB);
    float* fcbf = (float*)(ws + WS_FCB);
    float* rhf  = (float*)(ws + WS_RH);
    float* rwf  = (float*)(ws + WS_RW);
    int*   flag = (int*)(ws + WS_FLAG);
    u16*   qb   = (u16*)(ws + WS_Q);
    u16*   kvb  = (u16*)(ws + WS_KV);
    u16*   ctxb = (u16*)(ws + WS_CTX);

    k_detect<<<1, 64, 0, stream>>>((const u16*)x, flag);
    k_canon_xt<<<4096, 256, 0, stream>>>(x, xt, flag);
    k_canon_w<<<1024, 256, 0, stream>>>(wq, wkv, fcw, wb, fcwb, flag);
    k_canon_f<<<1, 256, 0, stream>>>(fcb,  fcbf, 256, flag);
    k_canon_f<<<4, 256, 0, stream>>>(relh, rhf,  864, flag);
    k_canon_f<<<4, 256, 0, stream>>>(relw, rwf,  864, flag);

    k_proj<<<512, 256, 0, stream>>>(xt, wb, qb, kvb);
    dim3 ga(256, 4);
    k_attn<<<ga, 512, 0, stream>>>(qb, kvb, rhf, rwf, ctxb);
    k_out<<<512, 256, 0, stream>>>(ctxb, fcwb, fcbf, d_out, flag);
}